// Round 1
// baseline (1064.684 us; speedup 1.0000x reference)
//
#include <hip/hip_runtime.h>
#include <math.h>

// MambaSSMBlock: B=2, L=2048, Dm=1024, Di=2048, N=16, convK=4
// Round 1: full fp32 correctness baseline. No MFMA yet (fp32 has no MFMA on CDNA4;
// bf16 MFMA swap planned for round 2 once absmax margin is measured).
// Workspace requirement: ~158 MB of d_ws.

#define B_SZ 2
#define LSEQ 2048
#define DM   1024
#define DI   2048
#define NS   16
#define RTOT (B_SZ*LSEQ)   // 4096 rows
#define NC   8             // scan chunks
#define TC   (LSEQ/NC)     // 256 steps per chunk

__device__ __forceinline__ float siluf(float v){ return v / (1.f + __expf(-v)); }

// ---------------- LayerNorm: one block per row ----------------
__global__ __launch_bounds__(256)
void ln_kernel(const float* __restrict__ x, const float* __restrict__ g,
               const float* __restrict__ b, float* __restrict__ xn) {
  __shared__ float red[8];
  const int r = blockIdx.x, tid = threadIdx.x;
  const float4 v = ((const float4*)(x + (size_t)r*DM))[tid];
  float s  = v.x+v.y+v.z+v.w;
  float ss = v.x*v.x+v.y*v.y+v.z*v.z+v.w*v.w;
  #pragma unroll
  for (int off=32; off; off>>=1){ s += __shfl_xor(s,off); ss += __shfl_xor(ss,off); }
  if ((tid & 63)==0){ int w=tid>>6; red[w]=s; red[4+w]=ss; }
  __syncthreads();
  s  = red[0]+red[1]+red[2]+red[3];
  ss = red[4]+red[5]+red[6]+red[7];
  const float mu  = s*(1.f/DM);
  const float inv = rsqrtf(ss*(1.f/DM) - mu*mu + 1e-5f);
  const float4 gv = ((const float4*)g)[tid];
  const float4 bv = ((const float4*)b)[tid];
  float4 o;
  o.x = (v.x-mu)*inv*gv.x + bv.x;
  o.y = (v.y-mu)*inv*gv.y + bv.y;
  o.z = (v.z-mu)*inv*gv.z + bv.z;
  o.w = (v.w-mu)*inv*gv.w + bv.w;
  ((float4*)(xn + (size_t)r*DM))[tid] = o;
}

// ---------------- fp32 NT GEMM: C[M][N] = A[M][K] * B[N][K]^T ----------------
// BM=BN=128, BK=16, 256 threads, 8x8 microtile. LDS stride 136 (pad +8): 2-way max.
__global__ __launch_bounds__(256)
void gemm_nt(const float* __restrict__ A, const float* __restrict__ B,
             float* __restrict__ C, int M, int N, int K) {
  __shared__ __align__(16) float As[16][136];
  __shared__ __align__(16) float Bs[16][136];
  const int tid = threadIdx.x;
  const int bm = blockIdx.y << 7;
  const int bn = blockIdx.x << 7;
  const int lr = tid >> 1;           // 0..127 (tile row loaded)
  const int lk = (tid & 1) << 3;     // 0 or 8 (k offset loaded)
  const int ty = tid >> 4;           // 0..15
  const int tx = tid & 15;           // 0..15
  float acc[8][8];
  #pragma unroll
  for (int i=0;i<8;i++)
    #pragma unroll
    for (int j=0;j<8;j++) acc[i][j]=0.f;
  const float* Ap = A + (size_t)(bm+lr)*K + lk;
  const float* Bp = B + (size_t)(bn+lr)*K + lk;
  for (int k0=0;k0<K;k0+=16){
    const float4 a0 = *(const float4*)(Ap + k0);
    const float4 a1 = *(const float4*)(Ap + k0 + 4);
    const float4 b0 = *(const float4*)(Bp + k0);
    const float4 b1 = *(const float4*)(Bp + k0 + 4);
    __syncthreads();
    As[lk+0][lr]=a0.x; As[lk+1][lr]=a0.y; As[lk+2][lr]=a0.z; As[lk+3][lr]=a0.w;
    As[lk+4][lr]=a1.x; As[lk+5][lr]=a1.y; As[lk+6][lr]=a1.z; As[lk+7][lr]=a1.w;
    Bs[lk+0][lr]=b0.x; Bs[lk+1][lr]=b0.y; Bs[lk+2][lr]=b0.z; Bs[lk+3][lr]=b0.w;
    Bs[lk+4][lr]=b1.x; Bs[lk+5][lr]=b1.y; Bs[lk+6][lr]=b1.z; Bs[lk+7][lr]=b1.w;
    __syncthreads();
    #pragma unroll
    for (int kk=0;kk<16;kk++){
      const float4 av0 = *(const float4*)&As[kk][ty<<3];
      const float4 av1 = *(const float4*)&As[kk][(ty<<3)+4];
      const float4 bv0 = *(const float4*)&Bs[kk][tx<<3];
      const float4 bv1 = *(const float4*)&Bs[kk][(tx<<3)+4];
      const float a_[8] = {av0.x,av0.y,av0.z,av0.w,av1.x,av1.y,av1.z,av1.w};
      const float b_[8] = {bv0.x,bv0.y,bv0.z,bv0.w,bv1.x,bv1.y,bv1.z,bv1.w};
      #pragma unroll
      for (int i=0;i<8;i++)
        #pragma unroll
        for (int j=0;j<8;j++) acc[i][j] = fmaf(a_[i], b_[j], acc[i][j]);
    }
  }
  #pragma unroll
  for (int i=0;i<8;i++){
    float* Cp = C + (size_t)(bm + (ty<<3) + i)*N + bn + (tx<<3);
    *(float4*)Cp     = make_float4(acc[i][0],acc[i][1],acc[i][2],acc[i][3]);
    *(float4*)(Cp+4) = make_float4(acc[i][4],acc[i][5],acc[i][6],acc[i][7]);
  }
}

// ---------------- depthwise causal conv K=4 + bias + SiLU ----------------
__global__ __launch_bounds__(256)
void conv_silu_kernel(const float* __restrict__ xpre, const float* __restrict__ cw,
                      const float* __restrict__ cb, float* __restrict__ xs) {
  const int idx = blockIdx.x * 256 + threadIdx.x;  // over RTOT * DI/4
  const int d4 = idx & (DI/4 - 1);
  const int r  = idx >> 9;
  const int b  = r >> 11;
  const int t  = r & (LSEQ-1);
  const int d  = d4 << 2;
  const float4 w0 = *(const float4*)(cw + (size_t)(d+0)*4);
  const float4 w1 = *(const float4*)(cw + (size_t)(d+1)*4);
  const float4 w2 = *(const float4*)(cw + (size_t)(d+2)*4);
  const float4 w3 = *(const float4*)(cw + (size_t)(d+3)*4);
  const float wk[4][4] = {{w0.x,w1.x,w2.x,w3.x},{w0.y,w1.y,w2.y,w3.y},
                          {w0.z,w1.z,w2.z,w3.z},{w0.w,w1.w,w2.w,w3.w}};
  float4 acc = *(const float4*)(cb + d);
  #pragma unroll
  for (int k=0;k<4;k++){
    const int tt = t - 3 + k;
    if (tt < 0) continue;
    const float4 xv = *(const float4*)(xpre + ((size_t)b*LSEQ + tt)*DI + d);
    acc.x = fmaf(wk[k][0], xv.x, acc.x);
    acc.y = fmaf(wk[k][1], xv.y, acc.y);
    acc.z = fmaf(wk[k][2], xv.z, acc.z);
    acc.w = fmaf(wk[k][3], xv.w, acc.w);
  }
  acc.x = siluf(acc.x); acc.y = siluf(acc.y); acc.z = siluf(acc.z); acc.w = siluf(acc.w);
  *(float4*)(xs + (size_t)r*DI + d) = acc;
}

// ---------------- xp = x_ssm @ W_xproj^T (33 outputs/row): one wave per row ----------------
__global__ __launch_bounds__(64)
void xp_kernel(const float* __restrict__ xs, const float* __restrict__ Wx,
               float* __restrict__ xp) {
  __shared__ __align__(16) float xl[DI];
  const int r = blockIdx.x;
  const int lane = threadIdx.x;
  const float4* xr = (const float4*)(xs + (size_t)r*DI);
  #pragma unroll
  for (int i=0;i<8;i++){ const int f4 = lane + 64*i; ((float4*)xl)[f4] = xr[f4]; }
  __syncthreads();
  for (int j=0;j<33;j++){
    const float4* wr = (const float4*)(Wx + (size_t)j*DI);
    float s = 0.f;
    #pragma unroll
    for (int i=0;i<8;i++){
      const int f4 = lane + 64*i;
      const float4 xv = ((const float4*)xl)[f4];
      const float4 wv = wr[f4];
      s += xv.x*wv.x + xv.y*wv.y + xv.z*wv.z + xv.w*wv.w;
    }
    #pragma unroll
    for (int off=32; off; off>>=1) s += __shfl_xor(s,off);
    if (lane==0) xp[(size_t)r*33 + j] = s;
  }
}

// ---------------- dt = softplus(xp @ W_dt^T + b_dt) + 1e-3 ----------------
// block: 256 channels x 64 rows, W_dt slice staged in LDS
__global__ __launch_bounds__(256)
void dt_kernel(const float* __restrict__ xp, const float* __restrict__ Wdt,
               const float* __restrict__ bdt, float* __restrict__ dt) {
  __shared__ float wl[256][34];
  const int tid = threadIdx.x;
  const int d0 = (blockIdx.x & 7) << 8;
  const int r0 = (blockIdx.x >> 3) << 6;
  for (int i = tid; i < 256*33; i += 256) wl[i/33][i%33] = Wdt[(size_t)d0*33 + i];
  const float bv = bdt[d0 + tid];
  __syncthreads();
  for (int rr=0; rr<64; ++rr){
    const int r = r0 + rr;
    const float* xpr = xp + (size_t)r*33;
    float s = bv;
    #pragma unroll
    for (int j=0;j<33;j++) s = fmaf(xpr[j], wl[tid][j], s);
    const float sp = (s > 20.f) ? s : log1pf(__expf(s));
    dt[(size_t)r*DI + d0 + tid] = sp + 0.001f;
  }
}

// ---------------- scan pass 1: local chunk scan (clip applied), emits y_loc, P, H ----
// thread quad (4 lanes) per (b,chunk,d); lane owns states n = nq*4..nq*4+3
__global__ __launch_bounds__(256)
void scan1_kernel(const float* __restrict__ xs, const float* __restrict__ dt,
                  const float* __restrict__ xp, const float* __restrict__ Alog,
                  const float* __restrict__ Dp,
                  float* __restrict__ y, float* __restrict__ Pbuf, float* __restrict__ Hbuf) {
  const int g  = blockIdx.x*256 + threadIdx.x;
  const int nq = g & 3;
  const int g2 = g >> 2;
  const int d  = g2 & (DI-1);
  const int bc = g2 >> 11;
  const int c  = bc & (NC-1);
  const int b  = bc >> 3;
  const float4 al = *(const float4*)(Alog + (size_t)d*NS + (nq<<2));
  const float Aa[4] = {-__expf(al.x), -__expf(al.y), -__expf(al.z), -__expf(al.w)};
  float rA[4];
  #pragma unroll
  for (int i=0;i<4;i++) rA[i] = 1.f/(Aa[i] + 1e-8f);
  const float Dv = Dp[d];
  float h[4] = {0,0,0,0};
  float P[4] = {1,1,1,1};
  const int t0 = c * TC;
  for (int t = t0; t < t0 + TC; ++t){
    const size_t r = (size_t)b*LSEQ + t;
    const float dtv = dt[r*DI + d];
    const float xv  = xs[r*DI + d];
    const float* xpr = xp + r*33;
    float e[4];
    #pragma unroll
    for (int i=0;i<4;i++){ e[i] = __expf(Aa[i]*dtv); P[i] *= e[i]; }
    float yp = 0.f;
    #pragma unroll
    for (int i=0;i<4;i++){
      const int n = (nq<<2) + i;
      const float Bv = xpr[1 + n];
      const float Cv = xpr[17 + n];
      const float gbx = rA[i] * (1.f - e[i]) * Bv * xv;
      h[i] = fmaf(e[i], h[i], gbx);
      h[i] = fminf(10.f, fmaxf(-10.f, h[i]));
      yp = fmaf(Cv, h[i], yp);
    }
    yp += __shfl_xor(yp, 1);
    yp += __shfl_xor(yp, 2);
    if (nq == 0) y[r*DI + d] = yp + Dv*xv;
  }
  const size_t pb = (((size_t)b*DI + d)*NC + c)*NS + (nq<<2);
  *(float4*)(Pbuf+pb) = make_float4(P[0],P[1],P[2],P[3]);
  *(float4*)(Hbuf+pb) = make_float4(h[0],h[1],h[2],h[3]);
}

// ---------------- scan pass 2: sequential chunk combine (tiny) ----------------
__global__ __launch_bounds__(256)
void scan2_kernel(const float* __restrict__ Pbuf, const float* __restrict__ Hbuf,
                  float* __restrict__ hin) {
  const int g = blockIdx.x*256 + threadIdx.x;  // B*DI*NS
  const int n = g & (NS-1);
  const int d = (g >> 4) & (DI-1);
  const int b = g >> 15;
  const size_t base = ((size_t)b*DI + d)*NC;
  float h = 0.f;
  hin[(base+0)*NS + n] = 0.f;
  for (int c=1;c<NC;++c){
    const float Pv = Pbuf[(base + c-1)*NS + n];
    const float Hv = Hbuf[(base + c-1)*NS + n];
    h = fmaf(Pv, h, Hv);
    hin[(base+c)*NS + n] = h;
  }
}

// ---------------- scan pass 3: cross-chunk correction + silu(z) fuse ----------------
__global__ __launch_bounds__(256)
void scan3_kernel(const float* __restrict__ dt, const float* __restrict__ xp,
                  const float* __restrict__ Alog, const float* __restrict__ hinb,
                  const float* __restrict__ z, float* __restrict__ y) {
  const int g  = blockIdx.x*256 + threadIdx.x;
  const int nq = g & 3;
  const int g2 = g >> 2;
  const int d  = g2 & (DI-1);
  const int bc = g2 >> 11;
  const int c  = bc & (NC-1);
  const int b  = bc >> 3;
  const float4 al = *(const float4*)(Alog + (size_t)d*NS + (nq<<2));
  const float Aa[4] = {-__expf(al.x), -__expf(al.y), -__expf(al.z), -__expf(al.w)};
  const size_t pb = (((size_t)b*DI + d)*NC + c)*NS + (nq<<2);
  const float4 hv = *(const float4*)(hinb + pb);
  const float hi[4] = {hv.x, hv.y, hv.z, hv.w};
  float q[4] = {1,1,1,1};
  const int t0 = c * TC;
  for (int t = t0; t < t0 + TC; ++t){
    const size_t r = (size_t)b*LSEQ + t;
    const float dtv = dt[r*DI + d];
    const float* xpr = xp + r*33;
    float cp = 0.f;
    #pragma unroll
    for (int i=0;i<4;i++){
      q[i] *= __expf(Aa[i]*dtv);
      const float Cv = xpr[17 + (nq<<2) + i];
      cp = fmaf(Cv*q[i], hi[i], cp);
    }
    cp += __shfl_xor(cp, 1);
    cp += __shfl_xor(cp, 2);
    if (nq == 0){
      const float zv = z[r*DI + d];
      y[r*DI + d] = (y[r*DI + d] + cp) * siluf(zv);
    }
  }
}

extern "C" void kernel_launch(void* const* d_in, const int* in_sizes, int n_in,
                              void* d_out, int out_size, void* d_ws, size_t ws_size,
                              hipStream_t stream) {
  const float* x     = (const float*)d_in[0];
  const float* gamma = (const float*)d_in[1];
  const float* beta  = (const float*)d_in[2];
  const float* W_in  = (const float*)d_in[3];
  const float* cw    = (const float*)d_in[4];
  const float* cb    = (const float*)d_in[5];
  const float* Alog  = (const float*)d_in[6];
  const float* Dp    = (const float*)d_in[7];
  const float* Wx    = (const float*)d_in[8];
  const float* Wdt   = (const float*)d_in[9];
  const float* bdt   = (const float*)d_in[10];
  const float* Wout  = (const float*)d_in[11];
  float* out = (float*)d_out;
  float* ws  = (float*)d_ws;

  const size_t M8 = 8u*1024u*1024u;
  float* xs_pre = ws;                 // 8M f32; dead after conv -> reused as y
  float* y      = ws;
  float* zb     = ws + M8;            // 8M
  float* xs     = ws + 2*M8;          // 8M
  float* dtb    = ws + 3*M8;          // 8M
  float* Pb     = ws + 4*M8;                        // 512K
  float* Hb     = ws + 4*M8 + 524288;               // 512K
  float* hinb   = ws + 4*M8 + 2*524288;             // 512K
  float* xnb    = ws + 4*M8 + 3*524288;             // 4M
  float* xpb    = ws + 4*M8 + 3*524288 + 4194304;   // 135168
  // total ~39.5M f32 = 158 MB

  ln_kernel<<<RTOT, 256, 0, stream>>>(x, gamma, beta, xnb);
  // xz = xn @ W_in^T, split halves: x_ssm_pre (rows 0..Di-1 of W_in), z (rows Di..)
  gemm_nt<<<dim3(DI/128, RTOT/128), 256, 0, stream>>>(xnb, W_in, xs_pre, RTOT, DI, DM);
  gemm_nt<<<dim3(DI/128, RTOT/128), 256, 0, stream>>>(xnb, W_in + (size_t)DI*DM, zb, RTOT, DI, DM);
  conv_silu_kernel<<<(RTOT*(DI/4))/256, 256, 0, stream>>>(xs_pre, cw, cb, xs);
  xp_kernel<<<RTOT, 64, 0, stream>>>(xs, Wx, xpb);
  dt_kernel<<<(DI/256)*(RTOT/64), 256, 0, stream>>>(xpb, Wdt, bdt, dtb);
  scan1_kernel<<<(B_SZ*NC*DI*4)/256, 256, 0, stream>>>(xs, dtb, xpb, Alog, Dp, y, Pb, Hb);
  scan2_kernel<<<(B_SZ*DI*NS)/256, 256, 0, stream>>>(Pb, Hb, hinb);
  scan3_kernel<<<(B_SZ*NC*DI*4)/256, 256, 0, stream>>>(dtb, xpb, Alog, hinb, zb, y);
  gemm_nt<<<dim3(DM/128, RTOT/128), 256, 0, stream>>>(y, Wout, out, RTOT, DM, DI);
}

// Round 2
// 620.730 us; speedup vs baseline: 1.7152x; 1.7152x over previous
//
#include <hip/hip_runtime.h>
#include <math.h>

// MambaSSMBlock: B=2, L=2048, Dm=1024, Di=2048, N=16, convK=4
// Round 2: GEMMs -> bf16x3 split-precision MFMA (no fp32 MFMA on CDNA4).
//   xz GEMM fused (N=4096), split fp32->bf16(hi,lo) fused into LN / scan3.
// Workspace: ~175 MB.

#define B_SZ 2
#define LSEQ 2048
#define DM   1024
#define DI   2048
#define NS   16
#define RTOT (B_SZ*LSEQ)   // 4096 rows
#define NC   8             // scan chunks
#define TC   (LSEQ/NC)     // 256 steps per chunk
#define XZL  4096          // xz leading dim (x_ssm cols 0..2047, z cols 2048..4095)

typedef __attribute__((ext_vector_type(8))) short bfrag;
typedef __attribute__((ext_vector_type(4))) float f32x4;

__device__ __forceinline__ float siluf(float v){ return v / (1.f + __expf(-v)); }

__device__ __forceinline__ unsigned short f2bf(float f){
  unsigned int u = __float_as_uint(f);
  u += 0x7FFFu + ((u >> 16) & 1u);
  return (unsigned short)(u >> 16);
}
__device__ __forceinline__ float bf2f(unsigned short h){
  return __uint_as_float(((unsigned int)h) << 16);
}

// ---------------- LayerNorm fused with bf16 hi/lo split ----------------
__global__ __launch_bounds__(256)
void ln_split_kernel(const float* __restrict__ x, const float* __restrict__ g,
                     const float* __restrict__ b,
                     unsigned short* __restrict__ xh, unsigned short* __restrict__ xl) {
  __shared__ float red[8];
  const int r = blockIdx.x, tid = threadIdx.x;
  const float4 v = ((const float4*)(x + (size_t)r*DM))[tid];
  float s  = v.x+v.y+v.z+v.w;
  float ss = v.x*v.x+v.y*v.y+v.z*v.z+v.w*v.w;
  #pragma unroll
  for (int off=32; off; off>>=1){ s += __shfl_xor(s,off); ss += __shfl_xor(ss,off); }
  if ((tid & 63)==0){ int w=tid>>6; red[w]=s; red[4+w]=ss; }
  __syncthreads();
  s  = red[0]+red[1]+red[2]+red[3];
  ss = red[4]+red[5]+red[6]+red[7];
  const float mu  = s*(1.f/DM);
  const float inv = rsqrtf(ss*(1.f/DM) - mu*mu + 1e-5f);
  const float4 gv = ((const float4*)g)[tid];
  const float4 bv = ((const float4*)b)[tid];
  float o[4];
  o[0] = (v.x-mu)*inv*gv.x + bv.x;
  o[1] = (v.y-mu)*inv*gv.y + bv.y;
  o[2] = (v.z-mu)*inv*gv.z + bv.z;
  o[3] = (v.w-mu)*inv*gv.w + bv.w;
  ushort4 h, l;
  h.x = f2bf(o[0]); l.x = f2bf(o[0] - bf2f(h.x));
  h.y = f2bf(o[1]); l.y = f2bf(o[1] - bf2f(h.y));
  h.z = f2bf(o[2]); l.z = f2bf(o[2] - bf2f(h.z));
  h.w = f2bf(o[3]); l.w = f2bf(o[3] - bf2f(h.w));
  ((ushort4*)(xh + (size_t)r*DM))[tid] = h;
  ((ushort4*)(xl + (size_t)r*DM))[tid] = l;
}

// ---------------- generic fp32 -> bf16 hi/lo split (weights) ----------------
__global__ __launch_bounds__(256)
void split_kernel(const float* __restrict__ in, unsigned short* __restrict__ hi,
                  unsigned short* __restrict__ lo, int n4) {
  const int i = blockIdx.x*256 + threadIdx.x;
  if (i >= n4) return;
  const float4 v = ((const float4*)in)[i];
  ushort4 h, l;
  h.x = f2bf(v.x); l.x = f2bf(v.x - bf2f(h.x));
  h.y = f2bf(v.y); l.y = f2bf(v.y - bf2f(h.y));
  h.z = f2bf(v.z); l.z = f2bf(v.z - bf2f(h.z));
  h.w = f2bf(v.w); l.w = f2bf(v.w - bf2f(h.w));
  ((ushort4*)hi)[i] = h;
  ((ushort4*)lo)[i] = l;
}

// ---------------- bf16x3 MFMA GEMM: C[M][N] = A[M][K] * B[N][K]^T ----------------
// A = Ah+Al, B = Bh+Bl (hi/lo bf16 split). acc += ah*bh + al*bh + ah*bl.
// 128x128 tile, BK=32, 256 thr (4 waves 2x2, each 64x64 = 4x4 frags of 16x16x32).
// LDS row stride 40 ushort (80B): frag ds_read_b128 2-way conflict (free).
__global__ __launch_bounds__(256)
void gemm_bf16x3(const unsigned short* __restrict__ Ah, const unsigned short* __restrict__ Al,
                 const unsigned short* __restrict__ Bh, const unsigned short* __restrict__ Bl,
                 float* __restrict__ C, int M, int N, int K, int ldc)
{
  __shared__ __align__(16) unsigned short lds[4][128][40];
  const int tid = threadIdx.x;
  const int bm = blockIdx.y << 7;
  const int bn = blockIdx.x << 7;
  const int wave = tid >> 6;
  const int lane = tid & 63;
  const int wm = (wave >> 1) << 6;
  const int wn = (wave & 1) << 6;
  const int fr = lane & 15;
  const int kg = lane >> 4;
  const int srow = tid >> 1;          // 0..127
  const int scol = (tid & 1) << 4;    // 0 or 16 (ushort units)

  const unsigned short* pAh = Ah + (size_t)(bm + srow)*K + scol;
  const unsigned short* pAl = Al + (size_t)(bm + srow)*K + scol;
  const unsigned short* pBh = Bh + (size_t)(bn + srow)*K + scol;
  const unsigned short* pBl = Bl + (size_t)(bn + srow)*K + scol;

  f32x4 acc[4][4];
  #pragma unroll
  for (int m=0;m<4;m++)
    #pragma unroll
    for (int n=0;n<4;n++)
      #pragma unroll
      for (int r=0;r<4;r++) acc[m][n][r] = 0.f;

  uint4 ra0, ra1, rb0, rb1, rc0, rc1, rd0, rd1;
#define LOAD8(k0) do { \
    ra0 = *(const uint4*)(pAh + (k0));     ra1 = *(const uint4*)(pAh + (k0) + 8); \
    rb0 = *(const uint4*)(pAl + (k0));     rb1 = *(const uint4*)(pAl + (k0) + 8); \
    rc0 = *(const uint4*)(pBh + (k0));     rc1 = *(const uint4*)(pBh + (k0) + 8); \
    rd0 = *(const uint4*)(pBl + (k0));     rd1 = *(const uint4*)(pBl + (k0) + 8); \
  } while(0)

  const int nIter = K >> 5;
  LOAD8(0);
  for (int it = 0; it < nIter; ++it) {
    __syncthreads();
    *(uint4*)&lds[0][srow][scol] = ra0;  *(uint4*)&lds[0][srow][scol+8] = ra1;
    *(uint4*)&lds[1][srow][scol] = rb0;  *(uint4*)&lds[1][srow][scol+8] = rb1;
    *(uint4*)&lds[2][srow][scol] = rc0;  *(uint4*)&lds[2][srow][scol+8] = rc1;
    *(uint4*)&lds[3][srow][scol] = rd0;  *(uint4*)&lds[3][srow][scol+8] = rd1;
    __syncthreads();
    if (it + 1 < nIter) LOAD8((size_t)(it+1) << 5);

    bfrag ah[4], al[4], bb[4];
    #pragma unroll
    for (int m=0;m<4;m++){
      ah[m] = *(const bfrag*)&lds[0][wm + (m<<4) + fr][kg<<3];
      al[m] = *(const bfrag*)&lds[1][wm + (m<<4) + fr][kg<<3];
    }
    #pragma unroll
    for (int n=0;n<4;n++) bb[n] = *(const bfrag*)&lds[2][wn + (n<<4) + fr][kg<<3];
    #pragma unroll
    for (int m=0;m<4;m++)
      #pragma unroll
      for (int n=0;n<4;n++){
        acc[m][n] = __builtin_amdgcn_mfma_f32_16x16x32_bf16(ah[m], bb[n], acc[m][n], 0, 0, 0);
        acc[m][n] = __builtin_amdgcn_mfma_f32_16x16x32_bf16(al[m], bb[n], acc[m][n], 0, 0, 0);
      }
    #pragma unroll
    for (int n=0;n<4;n++) bb[n] = *(const bfrag*)&lds[3][wn + (n<<4) + fr][kg<<3];
    #pragma unroll
    for (int m=0;m<4;m++)
      #pragma unroll
      for (int n=0;n<4;n++)
        acc[m][n] = __builtin_amdgcn_mfma_f32_16x16x32_bf16(ah[m], bb[n], acc[m][n], 0, 0, 0);
  }
#undef LOAD8

  // C/D layout: col = lane&15, row = (lane>>4)*4 + reg  [m89/m91 verified]
  #pragma unroll
  for (int m=0;m<4;m++)
    #pragma unroll
    for (int n=0;n<4;n++){
      float* Cp = C + (size_t)(bm + wm + (m<<4) + (kg<<2))*ldc + bn + wn + (n<<4) + fr;
      #pragma unroll
      for (int r=0;r<4;r++) Cp[(size_t)r*ldc] = acc[m][n][r];
    }
}

// ---------------- depthwise causal conv K=4 + bias + SiLU (reads strided xz) ----
__global__ __launch_bounds__(256)
void conv_silu_kernel(const float* __restrict__ xz, const float* __restrict__ cw,
                      const float* __restrict__ cb, float* __restrict__ xs) {
  const int idx = blockIdx.x * 256 + threadIdx.x;  // over RTOT * DI/4
  const int d4 = idx & (DI/4 - 1);
  const int r  = idx >> 9;
  const int b  = r >> 11;
  const int t  = r & (LSEQ-1);
  const int d  = d4 << 2;
  const float4 w0 = *(const float4*)(cw + (size_t)(d+0)*4);
  const float4 w1 = *(const float4*)(cw + (size_t)(d+1)*4);
  const float4 w2 = *(const float4*)(cw + (size_t)(d+2)*4);
  const float4 w3 = *(const float4*)(cw + (size_t)(d+3)*4);
  const float wk[4][4] = {{w0.x,w1.x,w2.x,w3.x},{w0.y,w1.y,w2.y,w3.y},
                          {w0.z,w1.z,w2.z,w3.z},{w0.w,w1.w,w2.w,w3.w}};
  float4 acc = *(const float4*)(cb + d);
  #pragma unroll
  for (int k=0;k<4;k++){
    const int tt = t - 3 + k;
    if (tt < 0) continue;
    const float4 xv = *(const float4*)(xz + ((size_t)b*LSEQ + tt)*XZL + d);
    acc.x = fmaf(wk[k][0], xv.x, acc.x);
    acc.y = fmaf(wk[k][1], xv.y, acc.y);
    acc.z = fmaf(wk[k][2], xv.z, acc.z);
    acc.w = fmaf(wk[k][3], xv.w, acc.w);
  }
  acc.x = siluf(acc.x); acc.y = siluf(acc.y); acc.z = siluf(acc.z); acc.w = siluf(acc.w);
  *(float4*)(xs + (size_t)r*DI + d) = acc;
}

// ---------------- xp = x_ssm @ W_xproj^T (33 outputs/row): one wave per row ----------------
__global__ __launch_bounds__(64)
void xp_kernel(const float* __restrict__ xs, const float* __restrict__ Wx,
               float* __restrict__ xp) {
  __shared__ __align__(16) float xl[DI];
  const int r = blockIdx.x;
  const int lane = threadIdx.x;
  const float4* xr = (const float4*)(xs + (size_t)r*DI);
  #pragma unroll
  for (int i=0;i<8;i++){ const int f4 = lane + 64*i; ((float4*)xl)[f4] = xr[f4]; }
  __syncthreads();
  for (int j=0;j<33;j++){
    const float4* wr = (const float4*)(Wx + (size_t)j*DI);
    float s = 0.f;
    #pragma unroll
    for (int i=0;i<8;i++){
      const int f4 = lane + 64*i;
      const float4 xv = ((const float4*)xl)[f4];
      const float4 wv = wr[f4];
      s += xv.x*wv.x + xv.y*wv.y + xv.z*wv.z + xv.w*wv.w;
    }
    #pragma unroll
    for (int off=32; off; off>>=1) s += __shfl_xor(s,off);
    if (lane==0) xp[(size_t)r*33 + j] = s;
  }
}

// ---------------- dt = softplus(xp @ W_dt^T + b_dt) + 1e-3 ----------------
__global__ __launch_bounds__(256)
void dt_kernel(const float* __restrict__ xp, const float* __restrict__ Wdt,
               const float* __restrict__ bdt, float* __restrict__ dt) {
  __shared__ float wl[256][34];
  const int tid = threadIdx.x;
  const int d0 = (blockIdx.x & 7) << 8;
  const int r0 = (blockIdx.x >> 3) << 6;
  for (int i = tid; i < 256*33; i += 256) wl[i/33][i%33] = Wdt[(size_t)d0*33 + i];
  const float bv = bdt[d0 + tid];
  __syncthreads();
  for (int rr=0; rr<64; ++rr){
    const int r = r0 + rr;
    const float* xpr = xp + (size_t)r*33;
    float s = bv;
    #pragma unroll
    for (int j=0;j<33;j++) s = fmaf(xpr[j], wl[tid][j], s);
    const float sp = (s > 20.f) ? s : log1pf(__expf(s));
    dt[(size_t)r*DI + d0 + tid] = sp + 0.001f;
  }
}

// ---------------- scan pass 1: local chunk scan -> y_loc (into xz x-half), P, H ----
__global__ __launch_bounds__(256)
void scan1_kernel(const float* __restrict__ xs, const float* __restrict__ dt,
                  const float* __restrict__ xp, const float* __restrict__ Alog,
                  const float* __restrict__ Dp,
                  float* __restrict__ y, float* __restrict__ Pbuf, float* __restrict__ Hbuf) {
  const int g  = blockIdx.x*256 + threadIdx.x;
  const int nq = g & 3;
  const int g2 = g >> 2;
  const int d  = g2 & (DI-1);
  const int bc = g2 >> 11;
  const int c  = bc & (NC-1);
  const int b  = bc >> 3;
  const float4 al = *(const float4*)(Alog + (size_t)d*NS + (nq<<2));
  const float Aa[4] = {-__expf(al.x), -__expf(al.y), -__expf(al.z), -__expf(al.w)};
  float rA[4];
  #pragma unroll
  for (int i=0;i<4;i++) rA[i] = 1.f/(Aa[i] + 1e-8f);
  const float Dv = Dp[d];
  float h[4] = {0,0,0,0};
  float P[4] = {1,1,1,1};
  const int t0 = c * TC;
  for (int t = t0; t < t0 + TC; ++t){
    const size_t r = (size_t)b*LSEQ + t;
    const float dtv = dt[r*DI + d];
    const float xv  = xs[r*DI + d];
    const float* xpr = xp + r*33;
    float e[4];
    #pragma unroll
    for (int i=0;i<4;i++){ e[i] = __expf(Aa[i]*dtv); P[i] *= e[i]; }
    float yp = 0.f;
    #pragma unroll
    for (int i=0;i<4;i++){
      const int n = (nq<<2) + i;
      const float Bv = xpr[1 + n];
      const float Cv = xpr[17 + n];
      const float gbx = rA[i] * (1.f - e[i]) * Bv * xv;
      h[i] = fmaf(e[i], h[i], gbx);
      h[i] = fminf(10.f, fmaxf(-10.f, h[i]));
      yp = fmaf(Cv, h[i], yp);
    }
    yp += __shfl_xor(yp, 1);
    yp += __shfl_xor(yp, 2);
    if (nq == 0) y[r*XZL + d] = yp + Dv*xv;
  }
  const size_t pb = (((size_t)b*DI + d)*NC + c)*NS + (nq<<2);
  *(float4*)(Pbuf+pb) = make_float4(P[0],P[1],P[2],P[3]);
  *(float4*)(Hbuf+pb) = make_float4(h[0],h[1],h[2],h[3]);
}

// ---------------- scan pass 2: sequential chunk combine (tiny) ----------------
__global__ __launch_bounds__(256)
void scan2_kernel(const float* __restrict__ Pbuf, const float* __restrict__ Hbuf,
                  float* __restrict__ hin) {
  const int g = blockIdx.x*256 + threadIdx.x;  // B*DI*NS
  const int n = g & (NS-1);
  const int d = (g >> 4) & (DI-1);
  const int b = g >> 15;
  const size_t base = ((size_t)b*DI + d)*NC;
  float h = 0.f;
  hin[(base+0)*NS + n] = 0.f;
  for (int c=1;c<NC;++c){
    const float Pv = Pbuf[(base + c-1)*NS + n];
    const float Hv = Hbuf[(base + c-1)*NS + n];
    h = fmaf(Pv, h, Hv);
    hin[(base+c)*NS + n] = h;
  }
}

// ---------------- scan pass 3: cross-chunk correction + silu(z) + bf16 split ----
__global__ __launch_bounds__(256)
void scan3_kernel(const float* __restrict__ dt, const float* __restrict__ xp,
                  const float* __restrict__ Alog, const float* __restrict__ hinb,
                  const float* __restrict__ xz,
                  unsigned short* __restrict__ yh, unsigned short* __restrict__ yl) {
  const int g  = blockIdx.x*256 + threadIdx.x;
  const int nq = g & 3;
  const int g2 = g >> 2;
  const int d  = g2 & (DI-1);
  const int bc = g2 >> 11;
  const int c  = bc & (NC-1);
  const int b  = bc >> 3;
  const float4 al = *(const float4*)(Alog + (size_t)d*NS + (nq<<2));
  const float Aa[4] = {-__expf(al.x), -__expf(al.y), -__expf(al.z), -__expf(al.w)};
  const size_t pb = (((size_t)b*DI + d)*NC + c)*NS + (nq<<2);
  const float4 hv = *(const float4*)(hinb + pb);
  const float hi[4] = {hv.x, hv.y, hv.z, hv.w};
  float q[4] = {1,1,1,1};
  const int t0 = c * TC;
  for (int t = t0; t < t0 + TC; ++t){
    const size_t r = (size_t)b*LSEQ + t;
    const float dtv = dt[r*DI + d];
    const float* xpr = xp + r*33;
    float cp = 0.f;
    #pragma unroll
    for (int i=0;i<4;i++){
      q[i] *= __expf(Aa[i]*dtv);
      const float Cv = xpr[17 + (nq<<2) + i];
      cp = fmaf(Cv*q[i], hi[i], cp);
    }
    cp += __shfl_xor(cp, 1);
    cp += __shfl_xor(cp, 2);
    if (nq == 0){
      const float zv = xz[r*XZL + 2048 + d];
      const float yv = (xz[r*XZL + d] + cp) * siluf(zv);
      const unsigned short h16 = f2bf(yv);
      yh[r*DI + d] = h16;
      yl[r*DI + d] = f2bf(yv - bf2f(h16));
    }
  }
}

extern "C" void kernel_launch(void* const* d_in, const int* in_sizes, int n_in,
                              void* d_out, int out_size, void* d_ws, size_t ws_size,
                              hipStream_t stream) {
  const float* x     = (const float*)d_in[0];
  const float* gamma = (const float*)d_in[1];
  const float* beta  = (const float*)d_in[2];
  const float* W_in  = (const float*)d_in[3];
  const float* cw    = (const float*)d_in[4];
  const float* cb    = (const float*)d_in[5];
  const float* Alog  = (const float*)d_in[6];
  const float* Dp    = (const float*)d_in[7];
  const float* Wx    = (const float*)d_in[8];
  const float* Wdt   = (const float*)d_in[9];
  const float* bdt   = (const float*)d_in[10];
  const float* Wout  = (const float*)d_in[11];
  float* out = (float*)d_out;
  float* ws  = (float*)d_ws;

  const size_t M1 = 1048576;
  float* xz   = ws;                 // 16M f32 (x_ssm pre-conv cols 0..2047 -> later y; z cols 2048..4095)
  float* xs   = ws + 16*M1;         // 8M
  float* dtb  = ws + 24*M1;         // 8M
  float* Pb   = ws + 32*M1;                         // 524288
  float* Hb   = Pb + 524288;                        // 524288
  float* hinb = Hb + 524288;                        // 524288
  float* xpb  = hinb + 524288;                      // 135168
  unsigned short* zone = (unsigned short*)(xpb + 135168);
  // gemm1 operands (dead after gemm1):
  unsigned short* xn_h = zone;             // 4M us
  unsigned short* xn_l = zone + 4*M1;      // 4M us
  unsigned short* Wi_h = zone + 8*M1;      // 4M us
  unsigned short* Wi_l = zone + 12*M1;     // 4M us
  // reuse for gemm3 A (written by scan3, after gemm1):
  unsigned short* y_h  = zone;             // 8M us
  unsigned short* y_l  = zone + 8*M1;      // 8M us
  unsigned short* Wo_h = zone + 16*M1;     // 2M us
  unsigned short* Wo_l = zone + 18*M1;     // 2M us
  // total: ~33.63M f32 + 10M f32-equiv = ~175 MB

  ln_split_kernel<<<RTOT, 256, 0, stream>>>(x, gamma, beta, xn_h, xn_l);
  split_kernel<<<(2*DI*DM/4 + 255)/256, 256, 0, stream>>>(W_in, Wi_h, Wi_l, 2*DI*DM/4);
  split_kernel<<<(DM*DI/4 + 255)/256, 256, 0, stream>>>(Wout, Wo_h, Wo_l, DM*DI/4);
  // xz = xn @ W_in^T  (fused both halves, N=4096)
  gemm_bf16x3<<<dim3(XZL/128, RTOT/128), 256, 0, stream>>>(xn_h, xn_l, Wi_h, Wi_l,
                                                           xz, RTOT, XZL, DM, XZL);
  conv_silu_kernel<<<(RTOT*(DI/4))/256, 256, 0, stream>>>(xz, cw, cb, xs);
  xp_kernel<<<RTOT, 64, 0, stream>>>(xs, Wx, xpb);
  dt_kernel<<<(DI/256)*(RTOT/64), 256, 0, stream>>>(xpb, Wdt, bdt, dtb);
  scan1_kernel<<<(B_SZ*NC*DI*4)/256, 256, 0, stream>>>(xs, dtb, xpb, Alog, Dp, xz, Pb, Hb);
  scan2_kernel<<<(B_SZ*DI*NS)/256, 256, 0, stream>>>(Pb, Hb, hinb);
  scan3_kernel<<<(B_SZ*NC*DI*4)/256, 256, 0, stream>>>(dtb, xpb, Alog, hinb, xz, y_h, y_l);
  // out = y @ W_out^T
  gemm_bf16x3<<<dim3(DM/128, RTOT/128), 256, 0, stream>>>(y_h, y_l, Wo_h, Wo_l,
                                                          out, RTOT, DM, DI, DM);
}

// Round 3
// 433.153 us; speedup vs baseline: 2.4580x; 1.4330x over previous
//
#include <hip/hip_runtime.h>
#include <math.h>

// MambaSSMBlock: B=2, L=2048, Dm=1024, Di=2048, N=16, convK=4
// Round 3: scan chunk count NC 8->32 (TC 256->64) for 4x thread-level
//   parallelism in the latency-bound scan passes; P/H/hin re-laid out
//   [c][b][d][n] for coalesced scan2. GEMMs unchanged (bf16x3 MFMA).
// Workspace: ~193 MB.

#define B_SZ 2
#define LSEQ 2048
#define DM   1024
#define DI   2048
#define NS   16
#define RTOT (B_SZ*LSEQ)   // 4096 rows
#define NC   32            // scan chunks
#define TC   (LSEQ/NC)     // 64 steps per chunk
#define XZL  4096          // xz leading dim (x_ssm cols 0..2047, z cols 2048..4095)

typedef __attribute__((ext_vector_type(8))) short bfrag;
typedef __attribute__((ext_vector_type(4))) float f32x4;

__device__ __forceinline__ float siluf(float v){ return v / (1.f + __expf(-v)); }

__device__ __forceinline__ unsigned short f2bf(float f){
  unsigned int u = __float_as_uint(f);
  u += 0x7FFFu + ((u >> 16) & 1u);
  return (unsigned short)(u >> 16);
}
__device__ __forceinline__ float bf2f(unsigned short h){
  return __uint_as_float(((unsigned int)h) << 16);
}

// ---------------- LayerNorm fused with bf16 hi/lo split ----------------
__global__ __launch_bounds__(256)
void ln_split_kernel(const float* __restrict__ x, const float* __restrict__ g,
                     const float* __restrict__ b,
                     unsigned short* __restrict__ xh, unsigned short* __restrict__ xl) {
  __shared__ float red[8];
  const int r = blockIdx.x, tid = threadIdx.x;
  const float4 v = ((const float4*)(x + (size_t)r*DM))[tid];
  float s  = v.x+v.y+v.z+v.w;
  float ss = v.x*v.x+v.y*v.y+v.z*v.z+v.w*v.w;
  #pragma unroll
  for (int off=32; off; off>>=1){ s += __shfl_xor(s,off); ss += __shfl_xor(ss,off); }
  if ((tid & 63)==0){ int w=tid>>6; red[w]=s; red[4+w]=ss; }
  __syncthreads();
  s  = red[0]+red[1]+red[2]+red[3];
  ss = red[4]+red[5]+red[6]+red[7];
  const float mu  = s*(1.f/DM);
  const float inv = rsqrtf(ss*(1.f/DM) - mu*mu + 1e-5f);
  const float4 gv = ((const float4*)g)[tid];
  const float4 bv = ((const float4*)b)[tid];
  float o[4];
  o[0] = (v.x-mu)*inv*gv.x + bv.x;
  o[1] = (v.y-mu)*inv*gv.y + bv.y;
  o[2] = (v.z-mu)*inv*gv.z + bv.z;
  o[3] = (v.w-mu)*inv*gv.w + bv.w;
  ushort4 h, l;
  h.x = f2bf(o[0]); l.x = f2bf(o[0] - bf2f(h.x));
  h.y = f2bf(o[1]); l.y = f2bf(o[1] - bf2f(h.y));
  h.z = f2bf(o[2]); l.z = f2bf(o[2] - bf2f(h.z));
  h.w = f2bf(o[3]); l.w = f2bf(o[3] - bf2f(h.w));
  ((ushort4*)(xh + (size_t)r*DM))[tid] = h;
  ((ushort4*)(xl + (size_t)r*DM))[tid] = l;
}

// ---------------- generic fp32 -> bf16 hi/lo split (weights) ----------------
__global__ __launch_bounds__(256)
void split_kernel(const float* __restrict__ in, unsigned short* __restrict__ hi,
                  unsigned short* __restrict__ lo, int n4) {
  const int i = blockIdx.x*256 + threadIdx.x;
  if (i >= n4) return;
  const float4 v = ((const float4*)in)[i];
  ushort4 h, l;
  h.x = f2bf(v.x); l.x = f2bf(v.x - bf2f(h.x));
  h.y = f2bf(v.y); l.y = f2bf(v.y - bf2f(h.y));
  h.z = f2bf(v.z); l.z = f2bf(v.z - bf2f(h.z));
  h.w = f2bf(v.w); l.w = f2bf(v.w - bf2f(h.w));
  ((ushort4*)hi)[i] = h;
  ((ushort4*)lo)[i] = l;
}

// ---------------- bf16x3 MFMA GEMM: C[M][N] = A[M][K] * B[N][K]^T ----------------
__global__ __launch_bounds__(256)
void gemm_bf16x3(const unsigned short* __restrict__ Ah, const unsigned short* __restrict__ Al,
                 const unsigned short* __restrict__ Bh, const unsigned short* __restrict__ Bl,
                 float* __restrict__ C, int M, int N, int K, int ldc)
{
  __shared__ __align__(16) unsigned short lds[4][128][40];
  const int tid = threadIdx.x;
  const int bm = blockIdx.y << 7;
  const int bn = blockIdx.x << 7;
  const int wave = tid >> 6;
  const int lane = tid & 63;
  const int wm = (wave >> 1) << 6;
  const int wn = (wave & 1) << 6;
  const int fr = lane & 15;
  const int kg = lane >> 4;
  const int srow = tid >> 1;          // 0..127
  const int scol = (tid & 1) << 4;    // 0 or 16 (ushort units)

  const unsigned short* pAh = Ah + (size_t)(bm + srow)*K + scol;
  const unsigned short* pAl = Al + (size_t)(bm + srow)*K + scol;
  const unsigned short* pBh = Bh + (size_t)(bn + srow)*K + scol;
  const unsigned short* pBl = Bl + (size_t)(bn + srow)*K + scol;

  f32x4 acc[4][4];
  #pragma unroll
  for (int m=0;m<4;m++)
    #pragma unroll
    for (int n=0;n<4;n++)
      #pragma unroll
      for (int r=0;r<4;r++) acc[m][n][r] = 0.f;

  uint4 ra0, ra1, rb0, rb1, rc0, rc1, rd0, rd1;
#define LOAD8(k0) do { \
    ra0 = *(const uint4*)(pAh + (k0));     ra1 = *(const uint4*)(pAh + (k0) + 8); \
    rb0 = *(const uint4*)(pAl + (k0));     rb1 = *(const uint4*)(pAl + (k0) + 8); \
    rc0 = *(const uint4*)(pBh + (k0));     rc1 = *(const uint4*)(pBh + (k0) + 8); \
    rd0 = *(const uint4*)(pBl + (k0));     rd1 = *(const uint4*)(pBl + (k0) + 8); \
  } while(0)

  const int nIter = K >> 5;
  LOAD8(0);
  for (int it = 0; it < nIter; ++it) {
    __syncthreads();
    *(uint4*)&lds[0][srow][scol] = ra0;  *(uint4*)&lds[0][srow][scol+8] = ra1;
    *(uint4*)&lds[1][srow][scol] = rb0;  *(uint4*)&lds[1][srow][scol+8] = rb1;
    *(uint4*)&lds[2][srow][scol] = rc0;  *(uint4*)&lds[2][srow][scol+8] = rc1;
    *(uint4*)&lds[3][srow][scol] = rd0;  *(uint4*)&lds[3][srow][scol+8] = rd1;
    __syncthreads();
    if (it + 1 < nIter) LOAD8((size_t)(it+1) << 5);

    bfrag ah[4], al[4], bb[4];
    #pragma unroll
    for (int m=0;m<4;m++){
      ah[m] = *(const bfrag*)&lds[0][wm + (m<<4) + fr][kg<<3];
      al[m] = *(const bfrag*)&lds[1][wm + (m<<4) + fr][kg<<3];
    }
    #pragma unroll
    for (int n=0;n<4;n++) bb[n] = *(const bfrag*)&lds[2][wn + (n<<4) + fr][kg<<3];
    #pragma unroll
    for (int m=0;m<4;m++)
      #pragma unroll
      for (int n=0;n<4;n++){
        acc[m][n] = __builtin_amdgcn_mfma_f32_16x16x32_bf16(ah[m], bb[n], acc[m][n], 0, 0, 0);
        acc[m][n] = __builtin_amdgcn_mfma_f32_16x16x32_bf16(al[m], bb[n], acc[m][n], 0, 0, 0);
      }
    #pragma unroll
    for (int n=0;n<4;n++) bb[n] = *(const bfrag*)&lds[3][wn + (n<<4) + fr][kg<<3];
    #pragma unroll
    for (int m=0;m<4;m++)
      #pragma unroll
      for (int n=0;n<4;n++)
        acc[m][n] = __builtin_amdgcn_mfma_f32_16x16x32_bf16(ah[m], bb[n], acc[m][n], 0, 0, 0);
  }
#undef LOAD8

  // C/D layout: col = lane&15, row = (lane>>4)*4 + reg  [m89/m91 verified]
  #pragma unroll
  for (int m=0;m<4;m++)
    #pragma unroll
    for (int n=0;n<4;n++){
      float* Cp = C + (size_t)(bm + wm + (m<<4) + (kg<<2))*ldc + bn + wn + (n<<4) + fr;
      #pragma unroll
      for (int r=0;r<4;r++) Cp[(size_t)r*ldc] = acc[m][n][r];
    }
}

// ---------------- depthwise causal conv K=4 + bias + SiLU (reads strided xz) ----
__global__ __launch_bounds__(256)
void conv_silu_kernel(const float* __restrict__ xz, const float* __restrict__ cw,
                      const float* __restrict__ cb, float* __restrict__ xs) {
  const int idx = blockIdx.x * 256 + threadIdx.x;  // over RTOT * DI/4
  const int d4 = idx & (DI/4 - 1);
  const int r  = idx >> 9;
  const int b  = r >> 11;
  const int t  = r & (LSEQ-1);
  const int d  = d4 << 2;
  const float4 w0 = *(const float4*)(cw + (size_t)(d+0)*4);
  const float4 w1 = *(const float4*)(cw + (size_t)(d+1)*4);
  const float4 w2 = *(const float4*)(cw + (size_t)(d+2)*4);
  const float4 w3 = *(const float4*)(cw + (size_t)(d+3)*4);
  const float wk[4][4] = {{w0.x,w1.x,w2.x,w3.x},{w0.y,w1.y,w2.y,w3.y},
                          {w0.z,w1.z,w2.z,w3.z},{w0.w,w1.w,w2.w,w3.w}};
  float4 acc = *(const float4*)(cb + d);
  #pragma unroll
  for (int k=0;k<4;k++){
    const int tt = t - 3 + k;
    if (tt < 0) continue;
    const float4 xv = *(const float4*)(xz + ((size_t)b*LSEQ + tt)*XZL + d);
    acc.x = fmaf(wk[k][0], xv.x, acc.x);
    acc.y = fmaf(wk[k][1], xv.y, acc.y);
    acc.z = fmaf(wk[k][2], xv.z, acc.z);
    acc.w = fmaf(wk[k][3], xv.w, acc.w);
  }
  acc.x = siluf(acc.x); acc.y = siluf(acc.y); acc.z = siluf(acc.z); acc.w = siluf(acc.w);
  *(float4*)(xs + (size_t)r*DI + d) = acc;
}

// ---------------- xp = x_ssm @ W_xproj^T (33 outputs/row): one wave per row ----------------
__global__ __launch_bounds__(64)
void xp_kernel(const float* __restrict__ xs, const float* __restrict__ Wx,
               float* __restrict__ xp) {
  __shared__ __align__(16) float xl[DI];
  const int r = blockIdx.x;
  const int lane = threadIdx.x;
  const float4* xr = (const float4*)(xs + (size_t)r*DI);
  #pragma unroll
  for (int i=0;i<8;i++){ const int f4 = lane + 64*i; ((float4*)xl)[f4] = xr[f4]; }
  __syncthreads();
  for (int j=0;j<33;j++){
    const float4* wr = (const float4*)(Wx + (size_t)j*DI);
    float s = 0.f;
    #pragma unroll
    for (int i=0;i<8;i++){
      const int f4 = lane + 64*i;
      const float4 xv = ((const float4*)xl)[f4];
      const float4 wv = wr[f4];
      s += xv.x*wv.x + xv.y*wv.y + xv.z*wv.z + xv.w*wv.w;
    }
    #pragma unroll
    for (int off=32; off; off>>=1) s += __shfl_xor(s,off);
    if (lane==0) xp[(size_t)r*33 + j] = s;
  }
}

// ---------------- dt = softplus(xp @ W_dt^T + b_dt) + 1e-3 ----------------
__global__ __launch_bounds__(256)
void dt_kernel(const float* __restrict__ xp, const float* __restrict__ Wdt,
               const float* __restrict__ bdt, float* __restrict__ dt) {
  __shared__ float wl[256][34];
  const int tid = threadIdx.x;
  const int d0 = (blockIdx.x & 7) << 8;
  const int r0 = (blockIdx.x >> 3) << 6;
  for (int i = tid; i < 256*33; i += 256) wl[i/33][i%33] = Wdt[(size_t)d0*33 + i];
  const float bv = bdt[d0 + tid];
  __syncthreads();
  for (int rr=0; rr<64; ++rr){
    const int r = r0 + rr;
    const float* xpr = xp + (size_t)r*33;
    float s = bv;
    #pragma unroll
    for (int j=0;j<33;j++) s = fmaf(xpr[j], wl[tid][j], s);
    const float sp = (s > 20.f) ? s : log1pf(__expf(s));
    dt[(size_t)r*DI + d0 + tid] = sp + 0.001f;
  }
}

// ---------------- scan pass 1: local chunk scan -> y_loc (into xz x-half), P, H ----
// thread quad per (b,c,d); lane owns 4 states. P/H layout: [c][b][d][n].
__global__ __launch_bounds__(256)
void scan1_kernel(const float* __restrict__ xs, const float* __restrict__ dt,
                  const float* __restrict__ xp, const float* __restrict__ Alog,
                  const float* __restrict__ Dp,
                  float* __restrict__ y, float* __restrict__ Pbuf, float* __restrict__ Hbuf) {
  const int g  = blockIdx.x*256 + threadIdx.x;
  const int nq = g & 3;
  const int g2 = g >> 2;
  const int d  = g2 & (DI-1);
  const int bc = g2 >> 11;
  const int c  = bc & (NC-1);
  const int b  = bc >> 5;
  const float4 al = *(const float4*)(Alog + (size_t)d*NS + (nq<<2));
  const float Aa[4] = {-__expf(al.x), -__expf(al.y), -__expf(al.z), -__expf(al.w)};
  float rA[4];
  #pragma unroll
  for (int i=0;i<4;i++) rA[i] = 1.f/(Aa[i] + 1e-8f);
  const float Dv = Dp[d];
  float h[4] = {0,0,0,0};
  float P[4] = {1,1,1,1};
  const int t0 = c * TC;
  for (int t = t0; t < t0 + TC; ++t){
    const size_t r = (size_t)b*LSEQ + t;
    const float dtv = dt[r*DI + d];
    const float xv  = xs[r*DI + d];
    const float* xpr = xp + r*33;
    float e[4];
    #pragma unroll
    for (int i=0;i<4;i++){ e[i] = __expf(Aa[i]*dtv); P[i] *= e[i]; }
    float yp = 0.f;
    #pragma unroll
    for (int i=0;i<4;i++){
      const int n = (nq<<2) + i;
      const float Bv = xpr[1 + n];
      const float Cv = xpr[17 + n];
      const float gbx = rA[i] * (1.f - e[i]) * Bv * xv;
      h[i] = fmaf(e[i], h[i], gbx);
      h[i] = fminf(10.f, fmaxf(-10.f, h[i]));
      yp = fmaf(Cv, h[i], yp);
    }
    yp += __shfl_xor(yp, 1);
    yp += __shfl_xor(yp, 2);
    if (nq == 0) y[r*XZL + d] = yp + Dv*xv;
  }
  const size_t pb = (((size_t)c*B_SZ + b)*DI + d)*NS + (nq<<2);
  *(float4*)(Pbuf+pb) = make_float4(P[0],P[1],P[2],P[3]);
  *(float4*)(Hbuf+pb) = make_float4(h[0],h[1],h[2],h[3]);
}

// ---------------- scan pass 2: sequential chunk combine ([c][b][d][n] coalesced) ----
__global__ __launch_bounds__(256)
void scan2_kernel(const float* __restrict__ Pbuf, const float* __restrict__ Hbuf,
                  float* __restrict__ hin) {
  const int g = blockIdx.x*256 + threadIdx.x;  // over B*DI*NS
  const size_t cs = (size_t)B_SZ*DI*NS;
  float h = 0.f;
  hin[g] = 0.f;
  for (int c=1;c<NC;++c){
    const float Pv = Pbuf[(size_t)(c-1)*cs + g];
    const float Hv = Hbuf[(size_t)(c-1)*cs + g];
    h = fmaf(Pv, h, Hv);
    hin[(size_t)c*cs + g] = h;
  }
}

// ---------------- scan pass 3: cross-chunk correction + silu(z) + bf16 split ----
__global__ __launch_bounds__(256)
void scan3_kernel(const float* __restrict__ dt, const float* __restrict__ xp,
                  const float* __restrict__ Alog, const float* __restrict__ hinb,
                  const float* __restrict__ xz,
                  unsigned short* __restrict__ yh, unsigned short* __restrict__ yl) {
  const int g  = blockIdx.x*256 + threadIdx.x;
  const int nq = g & 3;
  const int g2 = g >> 2;
  const int d  = g2 & (DI-1);
  const int bc = g2 >> 11;
  const int c  = bc & (NC-1);
  const int b  = bc >> 5;
  const float4 al = *(const float4*)(Alog + (size_t)d*NS + (nq<<2));
  const float Aa[4] = {-__expf(al.x), -__expf(al.y), -__expf(al.z), -__expf(al.w)};
  const size_t pb = (((size_t)c*B_SZ + b)*DI + d)*NS + (nq<<2);
  const float4 hv = *(const float4*)(hinb + pb);
  const float hi[4] = {hv.x, hv.y, hv.z, hv.w};
  float q[4] = {1,1,1,1};
  const int t0 = c * TC;
  for (int t = t0; t < t0 + TC; ++t){
    const size_t r = (size_t)b*LSEQ + t;
    const float dtv = dt[r*DI + d];
    const float* xpr = xp + r*33;
    float cp = 0.f;
    #pragma unroll
    for (int i=0;i<4;i++){
      q[i] *= __expf(Aa[i]*dtv);
      const float Cv = xpr[17 + (nq<<2) + i];
      cp = fmaf(Cv*q[i], hi[i], cp);
    }
    cp += __shfl_xor(cp, 1);
    cp += __shfl_xor(cp, 2);
    if (nq == 0){
      const float zv = xz[r*XZL + 2048 + d];
      const float yv = (xz[r*XZL + d] + cp) * siluf(zv);
      const unsigned short h16 = f2bf(yv);
      yh[r*DI + d] = h16;
      yl[r*DI + d] = f2bf(yv - bf2f(h16));
    }
  }
}

extern "C" void kernel_launch(void* const* d_in, const int* in_sizes, int n_in,
                              void* d_out, int out_size, void* d_ws, size_t ws_size,
                              hipStream_t stream) {
  const float* x     = (const float*)d_in[0];
  const float* gamma = (const float*)d_in[1];
  const float* beta  = (const float*)d_in[2];
  const float* W_in  = (const float*)d_in[3];
  const float* cw    = (const float*)d_in[4];
  const float* cb    = (const float*)d_in[5];
  const float* Alog  = (const float*)d_in[6];
  const float* Dp    = (const float*)d_in[7];
  const float* Wx    = (const float*)d_in[8];
  const float* Wdt   = (const float*)d_in[9];
  const float* bdt   = (const float*)d_in[10];
  const float* Wout  = (const float*)d_in[11];
  float* out = (float*)d_out;
  float* ws  = (float*)d_ws;

  const size_t M1 = 1048576;
  const size_t PH = (size_t)NC*B_SZ*DI*NS;          // 2M f32 per buffer
  float* xz   = ws;                 // 16M f32
  float* xs   = ws + 16*M1;         // 8M
  float* dtb  = ws + 24*M1;         // 8M
  float* Pb   = ws + 32*M1;         // 2M
  float* Hb   = Pb + PH;            // 2M
  float* hinb = Hb + PH;            // 2M
  float* xpb  = hinb + PH;          // 135168
  unsigned short* zone = (unsigned short*)(xpb + 135168);
  unsigned short* xn_h = zone;             // 4M us
  unsigned short* xn_l = zone + 4*M1;      // 4M us
  unsigned short* Wi_h = zone + 8*M1;      // 4M us
  unsigned short* Wi_l = zone + 12*M1;     // 4M us
  unsigned short* y_h  = zone;             // 8M us (reuse after gemm1)
  unsigned short* y_l  = zone + 8*M1;      // 8M us
  unsigned short* Wo_h = zone + 16*M1;     // 2M us
  unsigned short* Wo_l = zone + 18*M1;     // 2M us
  // total ~48.1M f32 = 193 MB

  ln_split_kernel<<<RTOT, 256, 0, stream>>>(x, gamma, beta, xn_h, xn_l);
  split_kernel<<<(2*DI*DM/4 + 255)/256, 256, 0, stream>>>(W_in, Wi_h, Wi_l, 2*DI*DM/4);
  split_kernel<<<(DM*DI/4 + 255)/256, 256, 0, stream>>>(Wout, Wo_h, Wo_l, DM*DI/4);
  gemm_bf16x3<<<dim3(XZL/128, RTOT/128), 256, 0, stream>>>(xn_h, xn_l, Wi_h, Wi_l,
                                                           xz, RTOT, XZL, DM, XZL);
  conv_silu_kernel<<<(RTOT*(DI/4))/256, 256, 0, stream>>>(xz, cw, cb, xs);
  xp_kernel<<<RTOT, 64, 0, stream>>>(xs, Wx, xpb);
  dt_kernel<<<(DI/256)*(RTOT/64), 256, 0, stream>>>(xpb, Wdt, bdt, dtb);
  scan1_kernel<<<(B_SZ*NC*DI*4)/256, 256, 0, stream>>>(xs, dtb, xpb, Alog, Dp, xz, Pb, Hb);
  scan2_kernel<<<(B_SZ*DI*NS)/256, 256, 0, stream>>>(Pb, Hb, hinb);
  scan3_kernel<<<(B_SZ*NC*DI*4)/256, 256, 0, stream>>>(dtb, xpb, Alog, hinb, xz, y_h, y_l);
  gemm_bf16x3<<<dim3(DM/128, RTOT/128), 256, 0, stream>>>(y_h, y_l, Wo_h, Wo_l,
                                                          out, RTOT, DM, DI, DM);
}

// Round 4
// 428.062 us; speedup vs baseline: 2.4872x; 1.0119x over previous
//
#include <hip/hip_runtime.h>
#include <math.h>

// MambaSSMBlock: B=2, L=2048, Dm=1024, Di=2048, N=16, convK=4
// Round 4: (1) out-GEMM 64x128 tile -> 512 blocks (2/CU) for latency hiding;
//          (2) scan NC 32->64 (TC=32); hin folded into Hbuf;
//          (3) y_h/y_l overlay dead xs; W_out split after gemm1.
// Workspace: ~192.5 MB (same as R3).

#define B_SZ 2
#define LSEQ 2048
#define DM   1024
#define DI   2048
#define NS   16
#define RTOT (B_SZ*LSEQ)   // 4096 rows
#define NC   64            // scan chunks
#define TC   (LSEQ/NC)     // 32 steps per chunk
#define XZL  4096          // xz leading dim (x_ssm cols 0..2047, z cols 2048..4095)

typedef __attribute__((ext_vector_type(8))) short bfrag;
typedef __attribute__((ext_vector_type(4))) float f32x4;
typedef unsigned short ushort_t;

__device__ __forceinline__ float siluf(float v){ return v / (1.f + __expf(-v)); }

__device__ __forceinline__ unsigned short f2bf(float f){
  unsigned int u = __float_as_uint(f);
  u += 0x7FFFu + ((u >> 16) & 1u);
  return (unsigned short)(u >> 16);
}
__device__ __forceinline__ float bf2f(unsigned short h){
  return __uint_as_float(((unsigned int)h) << 16);
}

// ---------------- LayerNorm fused with bf16 hi/lo split ----------------
__global__ __launch_bounds__(256)
void ln_split_kernel(const float* __restrict__ x, const float* __restrict__ g,
                     const float* __restrict__ b,
                     unsigned short* __restrict__ xh, unsigned short* __restrict__ xl) {
  __shared__ float red[8];
  const int r = blockIdx.x, tid = threadIdx.x;
  const float4 v = ((const float4*)(x + (size_t)r*DM))[tid];
  float s  = v.x+v.y+v.z+v.w;
  float ss = v.x*v.x+v.y*v.y+v.z*v.z+v.w*v.w;
  #pragma unroll
  for (int off=32; off; off>>=1){ s += __shfl_xor(s,off); ss += __shfl_xor(ss,off); }
  if ((tid & 63)==0){ int w=tid>>6; red[w]=s; red[4+w]=ss; }
  __syncthreads();
  s  = red[0]+red[1]+red[2]+red[3];
  ss = red[4]+red[5]+red[6]+red[7];
  const float mu  = s*(1.f/DM);
  const float inv = rsqrtf(ss*(1.f/DM) - mu*mu + 1e-5f);
  const float4 gv = ((const float4*)g)[tid];
  const float4 bv = ((const float4*)b)[tid];
  float o[4];
  o[0] = (v.x-mu)*inv*gv.x + bv.x;
  o[1] = (v.y-mu)*inv*gv.y + bv.y;
  o[2] = (v.z-mu)*inv*gv.z + bv.z;
  o[3] = (v.w-mu)*inv*gv.w + bv.w;
  ushort4 h, l;
  h.x = f2bf(o[0]); l.x = f2bf(o[0] - bf2f(h.x));
  h.y = f2bf(o[1]); l.y = f2bf(o[1] - bf2f(h.y));
  h.z = f2bf(o[2]); l.z = f2bf(o[2] - bf2f(h.z));
  h.w = f2bf(o[3]); l.w = f2bf(o[3] - bf2f(h.w));
  ((ushort4*)(xh + (size_t)r*DM))[tid] = h;
  ((ushort4*)(xl + (size_t)r*DM))[tid] = l;
}

// ---------------- generic fp32 -> bf16 hi/lo split (weights) ----------------
__global__ __launch_bounds__(256)
void split_kernel(const float* __restrict__ in, unsigned short* __restrict__ hi,
                  unsigned short* __restrict__ lo, int n4) {
  const int i = blockIdx.x*256 + threadIdx.x;
  if (i >= n4) return;
  const float4 v = ((const float4*)in)[i];
  ushort4 h, l;
  h.x = f2bf(v.x); l.x = f2bf(v.x - bf2f(h.x));
  h.y = f2bf(v.y); l.y = f2bf(v.y - bf2f(h.y));
  h.z = f2bf(v.z); l.z = f2bf(v.z - bf2f(h.z));
  h.w = f2bf(v.w); l.w = f2bf(v.w - bf2f(h.w));
  ((ushort4*)hi)[i] = h;
  ((ushort4*)lo)[i] = l;
}

// ---------------- bf16x3 MFMA GEMM 128x128: C = A * B^T ----------------
__global__ __launch_bounds__(256)
void gemm_bf16x3(const unsigned short* __restrict__ Ah, const unsigned short* __restrict__ Al,
                 const unsigned short* __restrict__ Bh, const unsigned short* __restrict__ Bl,
                 float* __restrict__ C, int M, int N, int K, int ldc)
{
  __shared__ __align__(16) unsigned short lds[4][128][40];
  const int tid = threadIdx.x;
  const int bm = blockIdx.y << 7;
  const int bn = blockIdx.x << 7;
  const int wave = tid >> 6;
  const int lane = tid & 63;
  const int wm = (wave >> 1) << 6;
  const int wn = (wave & 1) << 6;
  const int fr = lane & 15;
  const int kg = lane >> 4;
  const int srow = tid >> 1;          // 0..127
  const int scol = (tid & 1) << 4;    // 0 or 16 (ushort units)

  const unsigned short* pAh = Ah + (size_t)(bm + srow)*K + scol;
  const unsigned short* pAl = Al + (size_t)(bm + srow)*K + scol;
  const unsigned short* pBh = Bh + (size_t)(bn + srow)*K + scol;
  const unsigned short* pBl = Bl + (size_t)(bn + srow)*K + scol;

  f32x4 acc[4][4];
  #pragma unroll
  for (int m=0;m<4;m++)
    #pragma unroll
    for (int n=0;n<4;n++)
      #pragma unroll
      for (int r=0;r<4;r++) acc[m][n][r] = 0.f;

  uint4 ra0, ra1, rb0, rb1, rc0, rc1, rd0, rd1;
#define LOAD8(k0) do { \
    ra0 = *(const uint4*)(pAh + (k0));     ra1 = *(const uint4*)(pAh + (k0) + 8); \
    rb0 = *(const uint4*)(pAl + (k0));     rb1 = *(const uint4*)(pAl + (k0) + 8); \
    rc0 = *(const uint4*)(pBh + (k0));     rc1 = *(const uint4*)(pBh + (k0) + 8); \
    rd0 = *(const uint4*)(pBl + (k0));     rd1 = *(const uint4*)(pBl + (k0) + 8); \
  } while(0)

  const int nIter = K >> 5;
  LOAD8(0);
  for (int it = 0; it < nIter; ++it) {
    __syncthreads();
    *(uint4*)&lds[0][srow][scol] = ra0;  *(uint4*)&lds[0][srow][scol+8] = ra1;
    *(uint4*)&lds[1][srow][scol] = rb0;  *(uint4*)&lds[1][srow][scol+8] = rb1;
    *(uint4*)&lds[2][srow][scol] = rc0;  *(uint4*)&lds[2][srow][scol+8] = rc1;
    *(uint4*)&lds[3][srow][scol] = rd0;  *(uint4*)&lds[3][srow][scol+8] = rd1;
    __syncthreads();
    if (it + 1 < nIter) LOAD8((size_t)(it+1) << 5);

    bfrag ah[4], al[4], bb[4];
    #pragma unroll
    for (int m=0;m<4;m++){
      ah[m] = *(const bfrag*)&lds[0][wm + (m<<4) + fr][kg<<3];
      al[m] = *(const bfrag*)&lds[1][wm + (m<<4) + fr][kg<<3];
    }
    #pragma unroll
    for (int n=0;n<4;n++) bb[n] = *(const bfrag*)&lds[2][wn + (n<<4) + fr][kg<<3];
    #pragma unroll
    for (int m=0;m<4;m++)
      #pragma unroll
      for (int n=0;n<4;n++){
        acc[m][n] = __builtin_amdgcn_mfma_f32_16x16x32_bf16(ah[m], bb[n], acc[m][n], 0, 0, 0);
        acc[m][n] = __builtin_amdgcn_mfma_f32_16x16x32_bf16(al[m], bb[n], acc[m][n], 0, 0, 0);
      }
    #pragma unroll
    for (int n=0;n<4;n++) bb[n] = *(const bfrag*)&lds[3][wn + (n<<4) + fr][kg<<3];
    #pragma unroll
    for (int m=0;m<4;m++)
      #pragma unroll
      for (int n=0;n<4;n++)
        acc[m][n] = __builtin_amdgcn_mfma_f32_16x16x32_bf16(ah[m], bb[n], acc[m][n], 0, 0, 0);
  }
#undef LOAD8

  #pragma unroll
  for (int m=0;m<4;m++)
    #pragma unroll
    for (int n=0;n<4;n++){
      float* Cp = C + (size_t)(bm + wm + (m<<4) + (kg<<2))*ldc + bn + wn + (n<<4) + fr;
      #pragma unroll
      for (int r=0;r<4;r++) Cp[(size_t)r*ldc] = acc[m][n][r];
    }
}

// ---------------- bf16x3 MFMA GEMM 64x128 tile (for K-heavy out GEMM) ----------------
// 512 blocks -> 2 blocks/CU. 4 waves 2x2, each 32x64 = 2x4 frags.
__global__ __launch_bounds__(256)
void gemm_bf16x3_b64(const unsigned short* __restrict__ Ah, const unsigned short* __restrict__ Al,
                     const unsigned short* __restrict__ Bh, const unsigned short* __restrict__ Bl,
                     float* __restrict__ C, int M, int N, int K, int ldc)
{
  __shared__ __align__(16) unsigned short ldsA[2][64][40];
  __shared__ __align__(16) unsigned short ldsB[2][128][40];
  const int tid = threadIdx.x;
  const int bm = blockIdx.y << 6;
  const int bn = blockIdx.x << 7;
  const int wave = tid >> 6;
  const int lane = tid & 63;
  const int wm = (wave >> 1) << 5;    // 0 or 32
  const int wn = (wave & 1) << 6;     // 0 or 64
  const int fr = lane & 15;
  const int kg = lane >> 4;
  const int arow = tid >> 2, acol = (tid & 3) << 3;   // 64x32: 1 uint4/thread
  const int brow = tid >> 1, bcol = (tid & 1) << 4;   // 128x32: 2 uint4/thread

  const unsigned short* pAh = Ah + (size_t)(bm + arow)*K + acol;
  const unsigned short* pAl = Al + (size_t)(bm + arow)*K + acol;
  const unsigned short* pBh = Bh + (size_t)(bn + brow)*K + bcol;
  const unsigned short* pBl = Bl + (size_t)(bn + brow)*K + bcol;

  f32x4 acc[2][4];
  #pragma unroll
  for (int m=0;m<2;m++)
    #pragma unroll
    for (int n=0;n<4;n++)
      #pragma unroll
      for (int r=0;r<4;r++) acc[m][n][r] = 0.f;

  uint4 ra, rb, rc0, rc1, rd0, rd1;
#define LOAD6(k0) do { \
    ra  = *(const uint4*)(pAh + (k0)); \
    rb  = *(const uint4*)(pAl + (k0)); \
    rc0 = *(const uint4*)(pBh + (k0));  rc1 = *(const uint4*)(pBh + (k0) + 8); \
    rd0 = *(const uint4*)(pBl + (k0));  rd1 = *(const uint4*)(pBl + (k0) + 8); \
  } while(0)

  const int nIter = K >> 5;
  LOAD6(0);
  for (int it = 0; it < nIter; ++it) {
    __syncthreads();
    *(uint4*)&ldsA[0][arow][acol] = ra;
    *(uint4*)&ldsA[1][arow][acol] = rb;
    *(uint4*)&ldsB[0][brow][bcol] = rc0;  *(uint4*)&ldsB[0][brow][bcol+8] = rc1;
    *(uint4*)&ldsB[1][brow][bcol] = rd0;  *(uint4*)&ldsB[1][brow][bcol+8] = rd1;
    __syncthreads();
    if (it + 1 < nIter) LOAD6((size_t)(it+1) << 5);

    bfrag ah[2], al[2], bh[4], bl[4];
    #pragma unroll
    for (int m=0;m<2;m++){
      ah[m] = *(const bfrag*)&ldsA[0][wm + (m<<4) + fr][kg<<3];
      al[m] = *(const bfrag*)&ldsA[1][wm + (m<<4) + fr][kg<<3];
    }
    #pragma unroll
    for (int n=0;n<4;n++){
      bh[n] = *(const bfrag*)&ldsB[0][wn + (n<<4) + fr][kg<<3];
      bl[n] = *(const bfrag*)&ldsB[1][wn + (n<<4) + fr][kg<<3];
    }
    #pragma unroll
    for (int m=0;m<2;m++)
      #pragma unroll
      for (int n=0;n<4;n++){
        acc[m][n] = __builtin_amdgcn_mfma_f32_16x16x32_bf16(ah[m], bh[n], acc[m][n], 0, 0, 0);
        acc[m][n] = __builtin_amdgcn_mfma_f32_16x16x32_bf16(al[m], bh[n], acc[m][n], 0, 0, 0);
        acc[m][n] = __builtin_amdgcn_mfma_f32_16x16x32_bf16(ah[m], bl[n], acc[m][n], 0, 0, 0);
      }
  }
#undef LOAD6

  #pragma unroll
  for (int m=0;m<2;m++)
    #pragma unroll
    for (int n=0;n<4;n++){
      float* Cp = C + (size_t)(bm + wm + (m<<4) + (kg<<2))*ldc + bn + wn + (n<<4) + fr;
      #pragma unroll
      for (int r=0;r<4;r++) Cp[(size_t)r*ldc] = acc[m][n][r];
    }
}

// ---------------- depthwise causal conv K=4 + bias + SiLU (reads strided xz) ----
__global__ __launch_bounds__(256)
void conv_silu_kernel(const float* __restrict__ xz, const float* __restrict__ cw,
                      const float* __restrict__ cb, float* __restrict__ xs) {
  const int idx = blockIdx.x * 256 + threadIdx.x;  // over RTOT * DI/4
  const int d4 = idx & (DI/4 - 1);
  const int r  = idx >> 9;
  const int b  = r >> 11;
  const int t  = r & (LSEQ-1);
  const int d  = d4 << 2;
  const float4 w0 = *(const float4*)(cw + (size_t)(d+0)*4);
  const float4 w1 = *(const float4*)(cw + (size_t)(d+1)*4);
  const float4 w2 = *(const float4*)(cw + (size_t)(d+2)*4);
  const float4 w3 = *(const float4*)(cw + (size_t)(d+3)*4);
  const float wk[4][4] = {{w0.x,w1.x,w2.x,w3.x},{w0.y,w1.y,w2.y,w3.y},
                          {w0.z,w1.z,w2.z,w3.z},{w0.w,w1.w,w2.w,w3.w}};
  float4 acc = *(const float4*)(cb + d);
  #pragma unroll
  for (int k=0;k<4;k++){
    const int tt = t - 3 + k;
    if (tt < 0) continue;
    const float4 xv = *(const float4*)(xz + ((size_t)b*LSEQ + tt)*XZL + d);
    acc.x = fmaf(wk[k][0], xv.x, acc.x);
    acc.y = fmaf(wk[k][1], xv.y, acc.y);
    acc.z = fmaf(wk[k][2], xv.z, acc.z);
    acc.w = fmaf(wk[k][3], xv.w, acc.w);
  }
  acc.x = siluf(acc.x); acc.y = siluf(acc.y); acc.z = siluf(acc.z); acc.w = siluf(acc.w);
  *(float4*)(xs + (size_t)r*DI + d) = acc;
}

// ---------------- xp = x_ssm @ W_xproj^T (33 outputs/row) ----------------
__global__ __launch_bounds__(64)
void xp_kernel(const float* __restrict__ xs, const float* __restrict__ Wx,
               float* __restrict__ xp) {
  __shared__ __align__(16) float xl[DI];
  const int r = blockIdx.x;
  const int lane = threadIdx.x;
  const float4* xr = (const float4*)(xs + (size_t)r*DI);
  #pragma unroll
  for (int i=0;i<8;i++){ const int f4 = lane + 64*i; ((float4*)xl)[f4] = xr[f4]; }
  __syncthreads();
  for (int j=0;j<33;j++){
    const float4* wr = (const float4*)(Wx + (size_t)j*DI);
    float s = 0.f;
    #pragma unroll
    for (int i=0;i<8;i++){
      const int f4 = lane + 64*i;
      const float4 xv = ((const float4*)xl)[f4];
      const float4 wv = wr[f4];
      s += xv.x*wv.x + xv.y*wv.y + xv.z*wv.z + xv.w*wv.w;
    }
    #pragma unroll
    for (int off=32; off; off>>=1) s += __shfl_xor(s,off);
    if (lane==0) xp[(size_t)r*33 + j] = s;
  }
}

// ---------------- dt = softplus(xp @ W_dt^T + b_dt) + 1e-3 ----------------
__global__ __launch_bounds__(256)
void dt_kernel(const float* __restrict__ xp, const float* __restrict__ Wdt,
               const float* __restrict__ bdt, float* __restrict__ dt) {
  __shared__ float wl[256][34];
  const int tid = threadIdx.x;
  const int d0 = (blockIdx.x & 7) << 8;
  const int r0 = (blockIdx.x >> 3) << 6;
  for (int i = tid; i < 256*33; i += 256) wl[i/33][i%33] = Wdt[(size_t)d0*33 + i];
  const float bv = bdt[d0 + tid];
  __syncthreads();
  for (int rr=0; rr<64; ++rr){
    const int r = r0 + rr;
    const float* xpr = xp + (size_t)r*33;
    float s = bv;
    #pragma unroll
    for (int j=0;j<33;j++) s = fmaf(xpr[j], wl[tid][j], s);
    const float sp = (s > 20.f) ? s : log1pf(__expf(s));
    dt[(size_t)r*DI + d0 + tid] = sp + 0.001f;
  }
}

// ---------------- scan pass 1: local chunk scan -> y_loc (into xz x-half), P, H ----
// thread quad per (b,c,d); lane owns 4 states. P/H layout: [c][b][d][n].
__global__ __launch_bounds__(256)
void scan1_kernel(const float* __restrict__ xs, const float* __restrict__ dt,
                  const float* __restrict__ xp, const float* __restrict__ Alog,
                  const float* __restrict__ Dp,
                  float* __restrict__ y, float* __restrict__ Pbuf, float* __restrict__ Hbuf) {
  const int g  = blockIdx.x*256 + threadIdx.x;
  const int nq = g & 3;
  const int g2 = g >> 2;
  const int d  = g2 & (DI-1);
  const int bc = g2 >> 11;
  const int c  = bc & (NC-1);
  const int b  = bc >> 6;
  const float4 al = *(const float4*)(Alog + (size_t)d*NS + (nq<<2));
  const float Aa[4] = {-__expf(al.x), -__expf(al.y), -__expf(al.z), -__expf(al.w)};
  float rA[4];
  #pragma unroll
  for (int i=0;i<4;i++) rA[i] = 1.f/(Aa[i] + 1e-8f);
  const float Dv = Dp[d];
  float h[4] = {0,0,0,0};
  float P[4] = {1,1,1,1};
  const int t0 = c * TC;
  for (int t = t0; t < t0 + TC; ++t){
    const size_t r = (size_t)b*LSEQ + t;
    const float dtv = dt[r*DI + d];
    const float xv  = xs[r*DI + d];
    const float* xpr = xp + r*33;
    float e[4];
    #pragma unroll
    for (int i=0;i<4;i++){ e[i] = __expf(Aa[i]*dtv); P[i] *= e[i]; }
    float yp = 0.f;
    #pragma unroll
    for (int i=0;i<4;i++){
      const int n = (nq<<2) + i;
      const float Bv = xpr[1 + n];
      const float Cv = xpr[17 + n];
      const float gbx = rA[i] * (1.f - e[i]) * Bv * xv;
      h[i] = fmaf(e[i], h[i], gbx);
      h[i] = fminf(10.f, fmaxf(-10.f, h[i]));
      yp = fmaf(Cv, h[i], yp);
    }
    yp += __shfl_xor(yp, 1);
    yp += __shfl_xor(yp, 2);
    if (nq == 0) y[r*XZL + d] = yp + Dv*xv;
  }
  const size_t pb = (((size_t)c*B_SZ + b)*DI + d)*NS + (nq<<2);
  *(float4*)(Pbuf+pb) = make_float4(P[0],P[1],P[2],P[3]);
  *(float4*)(Hbuf+pb) = make_float4(h[0],h[1],h[2],h[3]);
}

// ---------------- scan pass 2: sequential chunk combine; hin folded into Hbuf ----
// After this kernel, Hbuf slot (c-1) holds h_in for chunk c (c>=1).
__global__ __launch_bounds__(256)
void scan2_kernel(const float* __restrict__ Pbuf, float* __restrict__ Hbuf) {
  const int g = blockIdx.x*256 + threadIdx.x;  // over B*DI*NS
  const size_t cs = (size_t)B_SZ*DI*NS;
  float h = 0.f;
  for (int c=1;c<NC;++c){
    const float Pv = Pbuf[(size_t)(c-1)*cs + g];
    const float Hv = Hbuf[(size_t)(c-1)*cs + g];
    h = fmaf(Pv, h, Hv);
    Hbuf[(size_t)(c-1)*cs + g] = h;
  }
}

// ---------------- scan pass 3: cross-chunk correction + silu(z) + bf16 split ----
__global__ __launch_bounds__(256)
void scan3_kernel(const float* __restrict__ dt, const float* __restrict__ xp,
                  const float* __restrict__ Alog, const float* __restrict__ hinb,
                  const float* __restrict__ xz,
                  unsigned short* __restrict__ yh, unsigned short* __restrict__ yl) {
  const int g  = blockIdx.x*256 + threadIdx.x;
  const int nq = g & 3;
  const int g2 = g >> 2;
  const int d  = g2 & (DI-1);
  const int bc = g2 >> 11;
  const int c  = bc & (NC-1);
  const int b  = bc >> 6;
  const float4 al = *(const float4*)(Alog + (size_t)d*NS + (nq<<2));
  const float Aa[4] = {-__expf(al.x), -__expf(al.y), -__expf(al.z), -__expf(al.w)};
  float hi[4] = {0.f, 0.f, 0.f, 0.f};
  if (c > 0){
    const size_t pb = (((size_t)(c-1)*B_SZ + b)*DI + d)*NS + (nq<<2);
    const float4 hv = *(const float4*)(hinb + pb);
    hi[0]=hv.x; hi[1]=hv.y; hi[2]=hv.z; hi[3]=hv.w;
  }
  float q[4] = {1,1,1,1};
  const int t0 = c * TC;
  for (int t = t0; t < t0 + TC; ++t){
    const size_t r = (size_t)b*LSEQ + t;
    const float dtv = dt[r*DI + d];
    const float* xpr = xp + r*33;
    float cp = 0.f;
    #pragma unroll
    for (int i=0;i<4;i++){
      q[i] *= __expf(Aa[i]*dtv);
      const float Cv = xpr[17 + (nq<<2) + i];
      cp = fmaf(Cv*q[i], hi[i], cp);
    }
    cp += __shfl_xor(cp, 1);
    cp += __shfl_xor(cp, 2);
    if (nq == 0){
      const float zv = xz[r*XZL + 2048 + d];
      const float yv = (xz[r*XZL + d] + cp) * siluf(zv);
      const unsigned short h16 = f2bf(yv);
      yh[r*DI + d] = h16;
      yl[r*DI + d] = f2bf(yv - bf2f(h16));
    }
  }
}

extern "C" void kernel_launch(void* const* d_in, const int* in_sizes, int n_in,
                              void* d_out, int out_size, void* d_ws, size_t ws_size,
                              hipStream_t stream) {
  const float* x     = (const float*)d_in[0];
  const float* gamma = (const float*)d_in[1];
  const float* beta  = (const float*)d_in[2];
  const float* W_in  = (const float*)d_in[3];
  const float* cw    = (const float*)d_in[4];
  const float* cb    = (const float*)d_in[5];
  const float* Alog  = (const float*)d_in[6];
  const float* Dp    = (const float*)d_in[7];
  const float* Wx    = (const float*)d_in[8];
  const float* Wdt   = (const float*)d_in[9];
  const float* bdt   = (const float*)d_in[10];
  const float* Wout  = (const float*)d_in[11];
  float* out = (float*)d_out;
  float* ws  = (float*)d_ws;

  const size_t M1 = 1048576;
  float* xz   = ws;                 // 16M f32
  float* xs   = ws + 16*M1;         // 8M f32; reused as y_h/y_l after scan1
  float* dtb  = ws + 24*M1;         // 8M
  float* Pb   = ws + 32*M1;         // 4M (NC*B*DI*NS = 4M exactly)
  float* Hb   = Pb + 4*M1;          // 4M (hin folded in by scan2)
  float* xpb  = Hb + 4*M1;          // 135168
  unsigned short* zone = (unsigned short*)(xpb + 135168);   // 16M ushort = 8M f32
  unsigned short* xn_h = zone;             // 4M us  (dead after gemm1)
  unsigned short* xn_l = zone + 4*M1;      // 4M us
  unsigned short* Wi_h = zone + 8*M1;      // 4M us
  unsigned short* Wi_l = zone + 12*M1;     // 4M us
  unsigned short* Wo_h = zone;             // 2M us (split AFTER gemm1, overlays xn_h)
  unsigned short* Wo_l = zone + 2*M1;      // 2M us
  unsigned short* y_h  = (unsigned short*)xs;          // 8M us (xs dead after scan1)
  unsigned short* y_l  = (unsigned short*)xs + 8*M1;   // 8M us
  // total ~48.13M f32 = 192.5 MB (same footprint as R3)

  ln_split_kernel<<<RTOT, 256, 0, stream>>>(x, gamma, beta, xn_h, xn_l);
  split_kernel<<<(2*DI*DM/4 + 255)/256, 256, 0, stream>>>(W_in, Wi_h, Wi_l, 2*DI*DM/4);
  gemm_bf16x3<<<dim3(XZL/128, RTOT/128), 256, 0, stream>>>(xn_h, xn_l, Wi_h, Wi_l,
                                                           xz, RTOT, XZL, DM, XZL);
  split_kernel<<<(DM*DI/4 + 255)/256, 256, 0, stream>>>(Wout, Wo_h, Wo_l, DM*DI/4);
  conv_silu_kernel<<<(RTOT*(DI/4))/256, 256, 0, stream>>>(xz, cw, cb, xs);
  xp_kernel<<<RTOT, 64, 0, stream>>>(xs, Wx, xpb);
  dt_kernel<<<(DI/256)*(RTOT/64), 256, 0, stream>>>(xpb, Wdt, bdt, dtb);
  scan1_kernel<<<(B_SZ*NC*DI*4)/256, 256, 0, stream>>>(xs, dtb, xpb, Alog, Dp, xz, Pb, Hb);
  scan2_kernel<<<(B_SZ*DI*NS)/256, 256, 0, stream>>>(Pb, Hb);
  scan3_kernel<<<(B_SZ*NC*DI*4)/256, 256, 0, stream>>>(dtb, xpb, Alog, Hb, xz, y_h, y_l);
  gemm_bf16x3_b64<<<dim3(DM/128, RTOT/64), 256, 0, stream>>>(y_h, y_l, Wo_h, Wo_l,
                                                             out, RTOT, DM, DI, DM);
}